// Round 12
// baseline (631.285 us; speedup 1.0000x reference)
//
#include <hip/hip_runtime.h>

#define B_ 256
#define T_ 2048
#define H_ 64

typedef float f32x4 __attribute__((ext_vector_type(4)));
typedef _Float16 h16x2 __attribute__((ext_vector_type(2)));
typedef _Float16 h16x8 __attribute__((ext_vector_type(8)));

__device__ __forceinline__ float fdot2(h16x2 a, h16x2 b, float c) {
#if __has_builtin(__builtin_amdgcn_fdot2)
    return __builtin_amdgcn_fdot2(a, b, c, false);   // v_dot2_f32_f16
#else
    float d;
    asm("v_dot2_f32_f16 %0, %1, %2, %3" : "=v"(d) : "v"(a), "v"(b), "v"(c));
    return d;
#endif
}

__device__ __forceinline__ float readlane_f(float v, int idx) {
    return __builtin_bit_cast(float,
        __builtin_amdgcn_readlane(__builtin_bit_cast(int, v), idx));
}

#define NLOG2E (-1.4426950408889634f)   // -log2(e): sigmoid prescale
#define TLOG2E ( 2.8853900817779268f)   // 2*log2(e): tanh prescale

// Single wave per batch row, zero barriers (measured-best structure), but
// weights now STREAM FROM LDS instead of registers. Rationale: R2-R11 all
// showed ~140 extra VALU instrs/step (VALUBusy ledger) because the register
// allocator refuses >116 arch VGPRs and parks the 96 weight registers in
// AGPRs, paying a v_accvgpr_read per dot2 use. LDS layout is transposed
// [gate][k-octet][lane][8xf16]: a wave's ds_read_b128 is 64x16B contiguous
// (m134's measured conflict-free pattern). Per step: 24 weight b128 reads +
// 8 broadcast h reads + 96 v_dot2 with ~60 live VGPRs -- nothing for the
// allocator to demote. LDS BW floor: 24KB/step / 128B/cyc = 192 cyc,
// overlapped with VALU issue.
__global__ __launch_bounds__(64, 1)
void gru_kernel(const float* __restrict__ x,
                const float* __restrict__ W_ih,
                const float* __restrict__ W_hh,
                const float* __restrict__ b_ih,
                const float* __restrict__ b_hh,
                float* __restrict__ out)
{
    __shared__ _Float16 wlds[3][8][64][8];      // 24 KB, [gate][octet][lane]
    __shared__ __align__(16) _Float16 shh[H_];  // h, f16 image

    const int lane = threadIdx.x;
    const int b    = blockIdx.x;

    // ---- stage prescaled f16 weights into LDS (one-time) ----
    #pragma unroll
    for (int g = 0; g < 3; ++g) {
        const float s = (g == 2) ? TLOG2E : NLOG2E;
        const float* wsrc = W_hh + (size_t)(g * 64 + lane) * H_;
        #pragma unroll
        for (int o = 0; o < 8; ++o) {
            h16x8 v;
            #pragma unroll
            for (int j = 0; j < 8; ++j) v[j] = (_Float16)(s * wsrc[o * 8 + j]);
            *(h16x8*)&wlds[g][o][lane][0] = v;   // ds_write_b128
        }
    }

    // x-side params, prescaled
    const float wihr = NLOG2E * W_ih[lane];
    const float wihz = NLOG2E * W_ih[64 + lane];
    const float wihn = TLOG2E * W_ih[128 + lane];
    const float br   = NLOG2E * (b_ih[lane]      + b_hh[lane]);
    const float bz   = NLOG2E * (b_ih[64 + lane] + b_hh[64 + lane]);
    const float bhn  = TLOG2E * b_hh[128 + lane];
    const float bin  = TLOG2E * b_ih[128 + lane];

    const float* __restrict__ xrow = x + (size_t)b * T_;
    float* __restrict__ orow = out + (size_t)b * T_;

    shh[lane] = (_Float16)0.0f;      // h0 = 0 (single wave: in-order LDS)

    float h_own = 0.0f;
    float oval  = 0.0f;
    float xa = xrow[lane];           // current 64-step block of x
    float xb = 0.0f;

    for (int tb = 0; tb < T_ / 64; ++tb) {
        if (tb < T_ / 64 - 1) xb = xrow[(tb + 1) * 64 + lane];

        #pragma unroll 4
        for (int t2 = 0; t2 < 64; ++t2) {
            const float xt  = readlane_f(xa, t2);
            const float xpr = fmaf(xt, wihr, br);
            const float xpz = fmaf(xt, wihz, bz);
            const float xpn = fmaf(xt, wihn, bin);

            // ---- h: 8 broadcast ds_read_b128 (64 f16 = 128 B) ----
            h16x2 hh[32];
            const f32x4* hp = (const f32x4*)shh;
            #pragma unroll
            for (int q = 0; q < 8; ++q) {
                union { f32x4 f; h16x2 h[4]; } u;
                u.f = hp[q];
                hh[4*q]   = u.h[0];
                hh[4*q+1] = u.h[1];
                hh[4*q+2] = u.h[2];
                hh[4*q+3] = u.h[3];
            }

            // ---- r-gate: 8 weight b128 reads + 32 dot2, sigmoid first ----
            float ar[4] = {0,0,0,0};
            #pragma unroll
            for (int o = 0; o < 8; ++o) {
                union { h16x8 v; h16x2 p[4]; } wv;
                wv.v = *(const h16x8*)&wlds[0][o][lane][0];
                const int a = o & 3;
                ar[a] = fdot2(wv.p[0], hh[4*o],   ar[a]);
                ar[a] = fdot2(wv.p[1], hh[4*o+1], ar[a]);
                ar[a] = fdot2(wv.p[2], hh[4*o+2], ar[a]);
                ar[a] = fdot2(wv.p[3], hh[4*o+3], ar[a]);
            }
            float sr = ((ar[0] + ar[1]) + (ar[2] + ar[3])) + xpr;
            float r  = __builtin_amdgcn_rcpf(1.0f + __builtin_amdgcn_exp2f(sr));

            // ---- z-gate ----
            float az[4] = {0,0,0,0};
            #pragma unroll
            for (int o = 0; o < 8; ++o) {
                union { h16x8 v; h16x2 p[4]; } wv;
                wv.v = *(const h16x8*)&wlds[1][o][lane][0];
                const int a = o & 3;
                az[a] = fdot2(wv.p[0], hh[4*o],   az[a]);
                az[a] = fdot2(wv.p[1], hh[4*o+1], az[a]);
                az[a] = fdot2(wv.p[2], hh[4*o+2], az[a]);
                az[a] = fdot2(wv.p[3], hh[4*o+3], az[a]);
            }
            float sz = ((az[0] + az[1]) + (az[2] + az[3])) + xpz;
            float z  = __builtin_amdgcn_rcpf(1.0f + __builtin_amdgcn_exp2f(sz));

            // ---- n-gate ----
            float an[4] = {0,0,0,0};
            #pragma unroll
            for (int o = 0; o < 8; ++o) {
                union { h16x8 v; h16x2 p[4]; } wv;
                wv.v = *(const h16x8*)&wlds[2][o][lane][0];
                const int a = o & 3;
                an[a] = fdot2(wv.p[0], hh[4*o],   an[a]);
                an[a] = fdot2(wv.p[1], hh[4*o+1], an[a]);
                an[a] = fdot2(wv.p[2], hh[4*o+2], an[a]);
                an[a] = fdot2(wv.p[3], hh[4*o+3], an[a]);
            }
            float hn  = ((an[0] + an[1]) + (an[2] + an[3])) + bhn;
            float pre = fmaf(r, hn, xpn);
            float n   = fmaf(-2.0f, __builtin_amdgcn_rcpf(
                              1.0f + __builtin_amdgcn_exp2f(pre)), 1.0f);

            float h_new = fmaf(z, h_own - n, n);   // (1-z)*n + z*h
            h_own = h_new;

            // publish FIRST: next step's read turnaround starts now
            shh[lane] = (_Float16)h_new;

            // output latch (off critical path)
            float h63 = readlane_f(h_new, 63);
            oval = (t2 == lane) ? h63 : oval;
        }

        orow[tb * 64 + lane] = oval;               // coalesced 256B store
        xa = xb;
    }
}

extern "C" void kernel_launch(void* const* d_in, const int* in_sizes, int n_in,
                              void* d_out, int out_size, void* d_ws, size_t ws_size,
                              hipStream_t stream) {
    const float* x    = (const float*)d_in[0];
    const float* W_ih = (const float*)d_in[1];
    const float* W_hh = (const float*)d_in[2];
    const float* b_ih = (const float*)d_in[3];
    const float* b_hh = (const float*)d_in[4];
    float* out = (float*)d_out;

    dim3 grid(B_), block(64);
    gru_kernel<<<grid, block, 0, stream>>>(x, W_ih, W_hh, b_ih, b_hh, out);
}

// Round 13
// 616.181 us; speedup vs baseline: 1.0245x; 1.0245x over previous
//
#include <hip/hip_runtime.h>

#define B_ 256
#define T_ 2048
#define H_ 64

typedef float f32x4 __attribute__((ext_vector_type(4)));
typedef _Float16 h16x2 __attribute__((ext_vector_type(2)));

__device__ __forceinline__ float fdot2(h16x2 a, h16x2 b, float c) {
#if __has_builtin(__builtin_amdgcn_fdot2)
    return __builtin_amdgcn_fdot2(a, b, c, false);   // v_dot2_f32_f16
#else
    float d;
    asm("v_dot2_f32_f16 %0, %1, %2, %3" : "=v"(d) : "v"(a), "v"(b), "v"(c));
    return d;
#endif
}

__device__ __forceinline__ float readlane_f(float v, int idx) {
    return __builtin_bit_cast(float,
        __builtin_amdgcn_readlane(__builtin_bit_cast(int, v), idx));
}

#define NLOG2E (-1.4426950408889634f)   // -log2(e): sigmoid prescale
#define TLOG2E ( 2.8853900817779268f)   // 2*log2(e): tanh prescale

// Single wave per row, zero barriers (measured-best). R13 experiment: the
// VALUBusy ledger across R11 (reg weights) and R12 (LDS weights) is only
// consistent with v_dot2_f32_f16 issuing at ~4cyc/wave64. fp32 peak
// arithmetic proves VOP3P packed FMA is full-rate (2cyc), so the 96 dot2s
// are replaced by 96 v_pk_fma_f16 (2 f16 MACs each, fp contract on h16x2
// math) accumulating in f16 over 4 chains x 8 terms per gate (err ~4e-4),
// folded to fp32 by 4 fdot2(acc,(1,1),.) per gate -- only 12 dot2s remain.
// If the rate hypothesis holds: busy 574 -> ~300 cyc/step.
__global__ __launch_bounds__(64, 1)
void gru_kernel(const float* __restrict__ x,
                const float* __restrict__ W_ih,
                const float* __restrict__ W_hh,
                const float* __restrict__ b_ih,
                const float* __restrict__ b_hh,
                float* __restrict__ out)
{
#pragma clang fp contract(fast)
    __shared__ __align__(16) _Float16 shh[H_];

    const int lane = threadIdx.x;
    const int b    = blockIdx.x;

    // ---- preload W_hh rows {lane, 64+lane, 128+lane}, prescale, cvt f16 ----
    h16x2 wr[32], wz[32], wn[32];
    {
        const f32x4* pr = (const f32x4*)(W_hh + (size_t)lane * H_);
        const f32x4* pz = (const f32x4*)(W_hh + (size_t)(64 + lane) * H_);
        const f32x4* pn = (const f32x4*)(W_hh + (size_t)(128 + lane) * H_);
        #pragma unroll
        for (int q = 0; q < 16; ++q) {
            f32x4 vr = pr[q], vz = pz[q], vn = pn[q];
            wr[2*q]   = h16x2{(_Float16)(NLOG2E * vr.x), (_Float16)(NLOG2E * vr.y)};
            wr[2*q+1] = h16x2{(_Float16)(NLOG2E * vr.z), (_Float16)(NLOG2E * vr.w)};
            wz[2*q]   = h16x2{(_Float16)(NLOG2E * vz.x), (_Float16)(NLOG2E * vz.y)};
            wz[2*q+1] = h16x2{(_Float16)(NLOG2E * vz.z), (_Float16)(NLOG2E * vz.w)};
            wn[2*q]   = h16x2{(_Float16)(TLOG2E * vn.x), (_Float16)(TLOG2E * vn.y)};
            wn[2*q+1] = h16x2{(_Float16)(TLOG2E * vn.z), (_Float16)(TLOG2E * vn.w)};
        }
    }
    #pragma unroll
    for (int i = 0; i < 32; ++i)
        asm volatile("" : "+v"(wr[i]), "+v"(wz[i]), "+v"(wn[i]));

    // x-side params, prescaled
    const float wihr = NLOG2E * W_ih[lane];
    const float wihz = NLOG2E * W_ih[64 + lane];
    const float wihn = TLOG2E * W_ih[128 + lane];
    const float br   = NLOG2E * (b_ih[lane]      + b_hh[lane]);
    const float bz   = NLOG2E * (b_ih[64 + lane] + b_hh[64 + lane]);
    const float bhn  = TLOG2E * b_hh[128 + lane];
    const float bin  = TLOG2E * b_ih[128 + lane];

    const h16x2 ones = h16x2{(_Float16)1.0f, (_Float16)1.0f};

    const float* __restrict__ xrow = x + (size_t)b * T_;
    float* __restrict__ orow = out + (size_t)b * T_;

    shh[lane] = (_Float16)0.0f;      // h0 = 0 (single wave: in-order LDS)

    float h_own = 0.0f;
    float oval  = 0.0f;
    float xa = xrow[lane];           // current 64-step block of x
    float xb = 0.0f;

    for (int tb = 0; tb < T_ / 64; ++tb) {
        if (tb < T_ / 64 - 1) xb = xrow[(tb + 1) * 64 + lane];

        #pragma unroll 4
        for (int t2 = 0; t2 < 64; ++t2) {
            const float xt  = readlane_f(xa, t2);
            const float xpr = fmaf(xt, wihr, br);
            const float xpz = fmaf(xt, wihz, bz);
            const float xpn = fmaf(xt, wihn, bin);

            // ---- h: 8 broadcast ds_read_b128 (64 f16 = 128 B) ----
            h16x2 hh[32];
            const f32x4* hp = (const f32x4*)shh;
            #pragma unroll
            for (int q = 0; q < 8; ++q) {
                union { f32x4 f; h16x2 h[4]; } u;
                u.f = hp[q];
                hh[4*q]   = u.h[0];
                hh[4*q+1] = u.h[1];
                hh[4*q+2] = u.h[2];
                hh[4*q+3] = u.h[3];
            }

            // ---- r-gate: 32 pk_fma_f16 (4 chains of 8) + 4 fdot2 fold ----
            h16x2 cr[4] = {h16x2{0,0}, h16x2{0,0}, h16x2{0,0}, h16x2{0,0}};
            #pragma unroll
            for (int i = 0; i < 32; ++i) cr[i >> 3] = wr[i] * hh[i] + cr[i >> 3];
            float sr = xpr;
            #pragma unroll
            for (int k = 0; k < 4; ++k) sr = fdot2(cr[k], ones, sr);
            float r  = __builtin_amdgcn_rcpf(1.0f + __builtin_amdgcn_exp2f(sr));

            // ---- z-gate ----
            h16x2 cz[4] = {h16x2{0,0}, h16x2{0,0}, h16x2{0,0}, h16x2{0,0}};
            #pragma unroll
            for (int i = 0; i < 32; ++i) cz[i >> 3] = wz[i] * hh[i] + cz[i >> 3];
            float sz = xpz;
            #pragma unroll
            for (int k = 0; k < 4; ++k) sz = fdot2(cz[k], ones, sz);
            float z  = __builtin_amdgcn_rcpf(1.0f + __builtin_amdgcn_exp2f(sz));

            // ---- n-gate ----
            h16x2 cn[4] = {h16x2{0,0}, h16x2{0,0}, h16x2{0,0}, h16x2{0,0}};
            #pragma unroll
            for (int i = 0; i < 32; ++i) cn[i >> 3] = wn[i] * hh[i] + cn[i >> 3];
            float hn = bhn;
            #pragma unroll
            for (int k = 0; k < 4; ++k) hn = fdot2(cn[k], ones, hn);
            float pre = fmaf(r, hn, xpn);
            float n   = fmaf(-2.0f, __builtin_amdgcn_rcpf(
                              1.0f + __builtin_amdgcn_exp2f(pre)), 1.0f);

            float h_new = fmaf(z, h_own - n, n);   // (1-z)*n + z*h
            h_own = h_new;

            // publish FIRST: next step's read turnaround starts now
            shh[lane] = (_Float16)h_new;

            // output latch (off critical path)
            float h63 = readlane_f(h_new, 63);
            oval = (t2 == lane) ? h63 : oval;
        }

        orow[tb * 64 + lane] = oval;               // coalesced 256B store
        xa = xb;
    }
}

extern "C" void kernel_launch(void* const* d_in, const int* in_sizes, int n_in,
                              void* d_out, int out_size, void* d_ws, size_t ws_size,
                              hipStream_t stream) {
    const float* x    = (const float*)d_in[0];
    const float* W_ih = (const float*)d_in[1];
    const float* W_hh = (const float*)d_in[2];
    const float* b_ih = (const float*)d_in[3];
    const float* b_hh = (const float*)d_in[4];
    float* out = (float*)d_out;

    dim3 grid(B_), block(64);
    gru_kernel<<<grid, block, 0, stream>>>(x, W_ih, W_hh, b_ih, b_hh, out);
}